// Round 5
// baseline (243.324 us; speedup 1.0000x reference)
//
#include <hip/hip_runtime.h>
#include <math.h>

#define WSZ 11
#define TX 64
#define TY 32
#define IN_H 42           // TY + 10
#define SIP 68            // si row stride (floats): 68 mod 32 = 4 -> row stagger
#define NF 4              // fields: a, b, a^2+b^2, ab
#define NTHREADS 256
#define NBLOCKS 2048

struct GW { float g[WSZ]; };

struct Win { float f3; float4 w1, w2, w3; float f16; };

__device__ __forceinline__ void load_win(const float* __restrict__ rowp, int Jb, Win& W) {
  const int i0 = 4 * Jb + 3;
  W.f3 = rowp[i0 < 0 ? 0 : i0];
  const int j1 = Jb + 1;
  W.w1 = *(const float4*)(rowp + 4 * (j1 < 0 ? 0 : j1));
  W.w2 = *(const float4*)(rowp + 4 * (Jb + 2));
  const int j3 = Jb + 3;
  W.w3 = *(const float4*)(rowp + 4 * (j3 > 127 ? 127 : j3));
  const int i4 = 4 * (Jb + 4);
  W.f16 = rowp[i4 > 511 ? 511 : i4];
}

__device__ __forceinline__ void win_fix(int Jb, Win& W) {
  if (4 * Jb + 3 < 0) W.f3 = 0.f;
  if (Jb + 1 < 0) W.w1 = make_float4(0.f, 0.f, 0.f, 0.f);
  if (Jb + 3 > 127) W.w3 = make_float4(0.f, 0.f, 0.f, 0.f);
  if (4 * (Jb + 4) > 511) W.f16 = 0.f;
}

__device__ __forceinline__ void win_vals(const Win& W, float v[14]) {
  v[0] = W.f3;
  v[1] = W.w1.x;  v[2] = W.w1.y;  v[3] = W.w1.z;  v[4] = W.w1.w;
  v[5] = W.w2.x;  v[6] = W.w2.y;  v[7] = W.w2.z;  v[8] = W.w2.w;
  v[9] = W.w3.x;  v[10] = W.w3.y; v[11] = W.w3.z; v[12] = W.w3.w;
  v[13] = W.f16;
}

__device__ __forceinline__ void fma4(float4& a, float g, const float4& v) {
  a.x = fmaf(g, v.x, a.x); a.y = fmaf(g, v.y, a.y);
  a.z = fmaf(g, v.z, a.z); a.w = fmaf(g, v.w, a.w);
}

// m1 = mu1, m2 = mu2, mss = E[a^2 + b^2], m12 = E[ab]
__device__ __forceinline__ float ssim_px(float m1, float m2, float mss, float m12) {
  const float C1 = 0.0001f, C2 = 0.0009f;
  const float mu1s = m1 * m1, mu2s = m2 * m2, mu12 = m1 * m2;
  const float num = (2.f * mu12 + C1) * (2.f * (m12 - mu12) + C2);
  const float den = (mu1s + mu2s + C1) * (mss - mu1s - mu2s + C2);
  return num * __builtin_amdgcn_rcpf(den);
}

__global__ __launch_bounds__(NTHREADS, 3) void ssim_main_kernel(
    const float* __restrict__ img1, const float* __restrict__ img2,
    float* __restrict__ partials, GW w, int nTiles)
{
  __shared__ __align__(16) float si[NF][IN_H][SIP];  // 45,696 B
  __shared__ float sred[NTHREADS / 64];

  const int tid = threadIdx.x;
  float accSum = 0.f;

  for (int tile = blockIdx.x; tile < nTiles; tile += gridDim.x) {
    int t = tile;
    const int tx = t & 7;   t >>= 3;   // 512/TX = 8
    const int ty = t & 15;  t >>= 4;   // 512/TY = 16
    const float* __restrict__ p1 = img1 + (size_t)t * 262144;
    const float* __restrict__ p2 = img2 + (size_t)t * 262144;
    const int gy0 = ty * TY - 5;

    // ---- horizontal pass: windows straight from global (L1), 4 px/item ----
    // items: 42 rows x 16 j-groups = 672
    for (int i = tid; i < IN_H * 16; i += NTHREADS) {
      const int r = i >> 4, j = i & 15;
      const int jw = j ^ ((r >> 1) & 1);  // bank swizzle (float4 granularity)
      const int gy = gy0 + r;
      if (gy >= 0 && gy < 512) {
        const int Jb = tx * 16 + j - 2;
        Win WA, WB;
        load_win(p1 + (size_t)gy * 512, Jb, WA);
        load_win(p2 + (size_t)gy * 512, Jb, WB);
        win_fix(Jb, WA); win_fix(Jb, WB);
        float a[14], b[14];
        win_vals(WA, a); win_vals(WB, b);
        float ss[14], ab[14];
#pragma unroll
        for (int q = 0; q < 14; q++) {
          ss[q] = fmaf(a[q], a[q], b[q] * b[q]);
          ab[q] = a[q] * b[q];
        }
        float m1[4] = {0, 0, 0, 0}, m2[4] = {0, 0, 0, 0},
              mss[4] = {0, 0, 0, 0}, m12[4] = {0, 0, 0, 0};
#pragma unroll
        for (int k = 0; k < WSZ; k++) {
          const float g = w.g[k];
#pragma unroll
          for (int x = 0; x < 4; x++) {
            m1[x]  = fmaf(g, a[x + k],  m1[x]);
            m2[x]  = fmaf(g, b[x + k],  m2[x]);
            mss[x] = fmaf(g, ss[x + k], mss[x]);
            m12[x] = fmaf(g, ab[x + k], m12[x]);
          }
        }
        *(float4*)&si[0][r][4 * jw] = make_float4(m1[0], m1[1], m1[2], m1[3]);
        *(float4*)&si[1][r][4 * jw] = make_float4(m2[0], m2[1], m2[2], m2[3]);
        *(float4*)&si[2][r][4 * jw] = make_float4(mss[0], mss[1], mss[2], mss[3]);
        *(float4*)&si[3][r][4 * jw] = make_float4(m12[0], m12[1], m12[2], m12[3]);
      } else {
        const float4 z = make_float4(0.f, 0.f, 0.f, 0.f);
#pragma unroll
        for (int f = 0; f < NF; f++) *(float4*)&si[f][r][4 * jw] = z;
      }
    }
    __syncthreads();

    // ---- vertical pass + SSIM: 4x x 2y per thread (256 items) ----
    {
      const int yi = tid >> 4, j = tid & 15;
      const int y0 = 2 * yi;
      float4 acc0[NF], acc1[NF];
#pragma unroll
      for (int f = 0; f < NF; f++) {
        acc0[f] = make_float4(0.f, 0.f, 0.f, 0.f);
        acc1[f] = make_float4(0.f, 0.f, 0.f, 0.f);
      }
#pragma unroll
      for (int k = 0; k < WSZ + 1; k++) {
        const int rr = y0 + k;
        const int jw = j ^ ((rr >> 1) & 1);  // same involution as writes
#pragma unroll
        for (int f = 0; f < NF; f++) {
          const float4 v = *(const float4*)&si[f][rr][4 * jw];
          if (k < WSZ) fma4(acc0[f], w.g[k], v);
          if (k >= 1)  fma4(acc1[f], w.g[k - 1], v);
        }
      }
      accSum += ssim_px(acc0[0].x, acc0[1].x, acc0[2].x, acc0[3].x);
      accSum += ssim_px(acc0[0].y, acc0[1].y, acc0[2].y, acc0[3].y);
      accSum += ssim_px(acc0[0].z, acc0[1].z, acc0[2].z, acc0[3].z);
      accSum += ssim_px(acc0[0].w, acc0[1].w, acc0[2].w, acc0[3].w);
      accSum += ssim_px(acc1[0].x, acc1[1].x, acc1[2].x, acc1[3].x);
      accSum += ssim_px(acc1[0].y, acc1[1].y, acc1[2].y, acc1[3].y);
      accSum += ssim_px(acc1[0].z, acc1[1].z, acc1[2].z, acc1[3].z);
      accSum += ssim_px(acc1[0].w, acc1[1].w, acc1[2].w, acc1[3].w);
    }
    __syncthreads();  // protect si before next tile overwrites
  }

  // ---- block reduction ----
  for (int off = 32; off > 0; off >>= 1)
    accSum += __shfl_down(accSum, off, 64);
  if ((tid & 63) == 0) sred[tid >> 6] = accSum;
  __syncthreads();
  if (tid == 0) {
    float s = 0.f;
#pragma unroll
    for (int i = 0; i < NTHREADS / 64; i++) s += sred[i];
    partials[blockIdx.x] = s;
  }
}

__global__ __launch_bounds__(256) void ssim_final_kernel(
    const float* __restrict__ partials, float* __restrict__ out,
    int n, double invN)
{
  __shared__ double sred[4];
  const int tid = threadIdx.x;
  double s = 0.0;
  for (int i = tid; i < n; i += 256) s += (double)partials[i];
  for (int off = 32; off > 0; off >>= 1)
    s += __shfl_down(s, off, 64);
  if ((tid & 63) == 0) sred[tid >> 6] = s;
  __syncthreads();
  if (tid == 0) {
    double tot = 0.0;
#pragma unroll
    for (int i = 0; i < 4; i++) tot += sred[i];
    out[0] = (float)(1.0 - tot * invN);
  }
}

extern "C" void kernel_launch(void* const* d_in, const int* in_sizes, int n_in,
                              void* d_out, int out_size, void* d_ws, size_t ws_size,
                              hipStream_t stream) {
  const float* img1 = (const float*)d_in[0];
  const float* img2 = (const float*)d_in[1];
  float* out = (float*)d_out;
  float* partials = (float*)d_ws;

  const int planes = in_sizes[0] / (512 * 512);     // 96
  const int nTiles = planes * 8 * 16;               // 12288

  GW w;
  {
    double g[WSZ], sum = 0.0;
    for (int i = 0; i < WSZ; i++) {
      const double x = (double)(i - WSZ / 2);
      g[i] = exp(-(x * x) / (2.0 * 1.5 * 1.5));
      sum += g[i];
    }
    for (int i = 0; i < WSZ; i++) w.g[i] = (float)(g[i] / sum);
  }

  const double invN = 1.0 / (double)in_sizes[0];

  ssim_main_kernel<<<NBLOCKS, NTHREADS, 0, stream>>>(img1, img2, partials, w, nTiles);
  ssim_final_kernel<<<1, 256, 0, stream>>>(partials, out, NBLOCKS, invN);
}

// Round 6
// 159.636 us; speedup vs baseline: 1.5242x; 1.5242x over previous
//
#include <hip/hip_runtime.h>
#include <math.h>

#define WSZ 11
#define TX 64
#define TY 32
#define IN_H 42           // TY + 10
#define SIP 68            // si row stride (floats)
#define NF 4              // fields: a, b, a^2+b^2, ab
#define NTHREADS 256
#define NBLOCKS 2048

struct GW { float g[WSZ]; };

struct Win { float f3; float4 w1, w2, w3; float f16; };

__device__ __forceinline__ void load_win(const float* __restrict__ rowp, int Jb, Win& W) {
  const int i0 = 4 * Jb + 3;
  W.f3 = rowp[i0 < 0 ? 0 : i0];
  const int j1 = Jb + 1;
  W.w1 = *(const float4*)(rowp + 4 * (j1 < 0 ? 0 : j1));
  W.w2 = *(const float4*)(rowp + 4 * (Jb + 2));
  const int j3 = Jb + 3;
  W.w3 = *(const float4*)(rowp + 4 * (j3 > 127 ? 127 : j3));
  const int i4 = 4 * (Jb + 4);
  W.f16 = rowp[i4 > 511 ? 511 : i4];
}

__device__ __forceinline__ void win_fix(int Jb, Win& W) {
  if (4 * Jb + 3 < 0) W.f3 = 0.f;
  if (Jb + 1 < 0) W.w1 = make_float4(0.f, 0.f, 0.f, 0.f);
  if (Jb + 3 > 127) W.w3 = make_float4(0.f, 0.f, 0.f, 0.f);
  if (4 * (Jb + 4) > 511) W.f16 = 0.f;
}

__device__ __forceinline__ void win_vals(const Win& W, float v[14]) {
  v[0] = W.f3;
  v[1] = W.w1.x;  v[2] = W.w1.y;  v[3] = W.w1.z;  v[4] = W.w1.w;
  v[5] = W.w2.x;  v[6] = W.w2.y;  v[7] = W.w2.z;  v[8] = W.w2.w;
  v[9] = W.w3.x;  v[10] = W.w3.y; v[11] = W.w3.z; v[12] = W.w3.w;
  v[13] = W.f16;
}

__device__ __forceinline__ void fma4(float4& a, float g, const float4& v) {
  a.x = fmaf(g, v.x, a.x); a.y = fmaf(g, v.y, a.y);
  a.z = fmaf(g, v.z, a.z); a.w = fmaf(g, v.w, a.w);
}

// m1 = mu1, m2 = mu2, mss = E[a^2 + b^2], m12 = E[ab]
__device__ __forceinline__ float ssim_px(float m1, float m2, float mss, float m12) {
  const float C1 = 0.0001f, C2 = 0.0009f;
  const float mu1s = m1 * m1, mu2s = m2 * m2, mu12 = m1 * m2;
  const float num = (2.f * mu12 + C1) * (2.f * (m12 - mu12) + C2);
  const float den = (mu1s + mu2s + C1) * (mss - mu1s - mu2s + C2);
  return num * __builtin_amdgcn_rcpf(den);
}

__global__ __launch_bounds__(NTHREADS, 2) void ssim_main_kernel(
    const float* __restrict__ img1, const float* __restrict__ img2,
    float* __restrict__ partials, GW w, int nTiles)
{
  __shared__ __align__(16) float si[NF][IN_H][SIP];  // 45,696 B -> 3 blocks/CU via LDS
  __shared__ float sred[NTHREADS / 64];

  const int tid = threadIdx.x;
  float accSum = 0.f;

  for (int tile = blockIdx.x; tile < nTiles; tile += gridDim.x) {
    int t = tile;
    const int tx = t & 7;   t >>= 3;   // 512/TX = 8
    const int ty = t & 15;  t >>= 4;   // 512/TY = 16
    const float* __restrict__ p1 = img1 + (size_t)t * 262144;
    const float* __restrict__ p2 = img2 + (size_t)t * 262144;
    const int gy0 = ty * TY - 5;

    // ---- horizontal pass: windows straight from global (L1), 4 px/item ----
    for (int i = tid; i < IN_H * 16; i += NTHREADS) {
      const int r = i >> 4, j = i & 15;
      const int jw = j ^ ((r >> 1) & 1);  // bank swizzle (float4 granularity)
      const int gy = gy0 + r;
      if (gy >= 0 && gy < 512) {
        const int Jb = tx * 16 + j - 2;
        Win WA, WB;
        load_win(p1 + (size_t)gy * 512, Jb, WA);
        load_win(p2 + (size_t)gy * 512, Jb, WB);
        win_fix(Jb, WA); win_fix(Jb, WB);
        float a[14], b[14];
        win_vals(WA, a); win_vals(WB, b);
        float ss[14], ab[14];
#pragma unroll
        for (int q = 0; q < 14; q++) {
          ss[q] = fmaf(a[q], a[q], b[q] * b[q]);
          ab[q] = a[q] * b[q];
        }
        float m1[4] = {0, 0, 0, 0}, m2[4] = {0, 0, 0, 0},
              mss[4] = {0, 0, 0, 0}, m12[4] = {0, 0, 0, 0};
#pragma unroll
        for (int k = 0; k < WSZ; k++) {
          const float g = w.g[k];
#pragma unroll
          for (int x = 0; x < 4; x++) {
            m1[x]  = fmaf(g, a[x + k],  m1[x]);
            m2[x]  = fmaf(g, b[x + k],  m2[x]);
            mss[x] = fmaf(g, ss[x + k], mss[x]);
            m12[x] = fmaf(g, ab[x + k], m12[x]);
          }
        }
        *(float4*)&si[0][r][4 * jw] = make_float4(m1[0], m1[1], m1[2], m1[3]);
        *(float4*)&si[1][r][4 * jw] = make_float4(m2[0], m2[1], m2[2], m2[3]);
        *(float4*)&si[2][r][4 * jw] = make_float4(mss[0], mss[1], mss[2], mss[3]);
        *(float4*)&si[3][r][4 * jw] = make_float4(m12[0], m12[1], m12[2], m12[3]);
      } else {
        const float4 z = make_float4(0.f, 0.f, 0.f, 0.f);
#pragma unroll
        for (int f = 0; f < NF; f++) *(float4*)&si[f][r][4 * jw] = z;
      }
    }
    __syncthreads();

    // ---- vertical pass + SSIM: 4x x 2y per thread (256 items) ----
    {
      const int yi = tid >> 4, j = tid & 15;
      const int y0 = 2 * yi;
      float4 acc0[NF], acc1[NF];
#pragma unroll
      for (int f = 0; f < NF; f++) {
        acc0[f] = make_float4(0.f, 0.f, 0.f, 0.f);
        acc1[f] = make_float4(0.f, 0.f, 0.f, 0.f);
      }
#pragma unroll
      for (int k = 0; k < WSZ + 1; k++) {
        const int rr = y0 + k;
        const int jw = j ^ ((rr >> 1) & 1);  // same involution as writes
#pragma unroll
        for (int f = 0; f < NF; f++) {
          const float4 v = *(const float4*)&si[f][rr][4 * jw];
          if (k < WSZ) fma4(acc0[f], w.g[k], v);
          if (k >= 1)  fma4(acc1[f], w.g[k - 1], v);
        }
      }
      accSum += ssim_px(acc0[0].x, acc0[1].x, acc0[2].x, acc0[3].x);
      accSum += ssim_px(acc0[0].y, acc0[1].y, acc0[2].y, acc0[3].y);
      accSum += ssim_px(acc0[0].z, acc0[1].z, acc0[2].z, acc0[3].z);
      accSum += ssim_px(acc0[0].w, acc0[1].w, acc0[2].w, acc0[3].w);
      accSum += ssim_px(acc1[0].x, acc1[1].x, acc1[2].x, acc1[3].x);
      accSum += ssim_px(acc1[0].y, acc1[1].y, acc1[2].y, acc1[3].y);
      accSum += ssim_px(acc1[0].z, acc1[1].z, acc1[2].z, acc1[3].z);
      accSum += ssim_px(acc1[0].w, acc1[1].w, acc1[2].w, acc1[3].w);
    }
    __syncthreads();  // protect si before next tile overwrites
  }

  // ---- block reduction ----
  for (int off = 32; off > 0; off >>= 1)
    accSum += __shfl_down(accSum, off, 64);
  if ((tid & 63) == 0) sred[tid >> 6] = accSum;
  __syncthreads();
  if (tid == 0) {
    float s = 0.f;
#pragma unroll
    for (int i = 0; i < NTHREADS / 64; i++) s += sred[i];
    partials[blockIdx.x] = s;
  }
}

__global__ __launch_bounds__(256) void ssim_final_kernel(
    const float* __restrict__ partials, float* __restrict__ out,
    int n, double invN)
{
  __shared__ double sred[4];
  const int tid = threadIdx.x;
  double s = 0.0;
  for (int i = tid; i < n; i += 256) s += (double)partials[i];
  for (int off = 32; off > 0; off >>= 1)
    s += __shfl_down(s, off, 64);
  if ((tid & 63) == 0) sred[tid >> 6] = s;
  __syncthreads();
  if (tid == 0) {
    double tot = 0.0;
#pragma unroll
    for (int i = 0; i < 4; i++) tot += sred[i];
    out[0] = (float)(1.0 - tot * invN);
  }
}

extern "C" void kernel_launch(void* const* d_in, const int* in_sizes, int n_in,
                              void* d_out, int out_size, void* d_ws, size_t ws_size,
                              hipStream_t stream) {
  const float* img1 = (const float*)d_in[0];
  const float* img2 = (const float*)d_in[1];
  float* out = (float*)d_out;
  float* partials = (float*)d_ws;

  const int planes = in_sizes[0] / (512 * 512);     // 96
  const int nTiles = planes * 8 * 16;               // 12288

  GW w;
  {
    double g[WSZ], sum = 0.0;
    for (int i = 0; i < WSZ; i++) {
      const double x = (double)(i - WSZ / 2);
      g[i] = exp(-(x * x) / (2.0 * 1.5 * 1.5));
      sum += g[i];
    }
    for (int i = 0; i < WSZ; i++) w.g[i] = (float)(g[i] / sum);
  }

  const double invN = 1.0 / (double)in_sizes[0];

  ssim_main_kernel<<<NBLOCKS, NTHREADS, 0, stream>>>(img1, img2, partials, w, nTiles);
  ssim_final_kernel<<<1, 256, 0, stream>>>(partials, out, NBLOCKS, invN);
}

// Round 7
// 128.850 us; speedup vs baseline: 1.8884x; 1.2389x over previous
//
#include <hip/hip_runtime.h>
#include <math.h>

#define WSZ 11
#define TX 64
#define TY 64
#define IN_H 74           // TY + 10
#define SIP 66            // si row stride (floats): 4-apart rows -> banks +8
#define NF 4              // fields: a, b, a^2+b^2, ab
#define NTHREADS 256
#define NBLOCKS 2048

struct GW { float g[WSZ]; };

struct Win { float f3; float4 w1, w2, w3; float f16; };

__device__ __forceinline__ void load_win_clamped(const float* __restrict__ rowp,
                                                 int Jb, Win& W) {
  const int i0 = 4 * Jb + 3;
  W.f3 = rowp[i0 < 0 ? 0 : i0];
  const int j1 = Jb + 1;
  W.w1 = *(const float4*)(rowp + 4 * (j1 < 0 ? 0 : j1));
  W.w2 = *(const float4*)(rowp + 4 * (Jb + 2));
  const int j3 = Jb + 3;
  W.w3 = *(const float4*)(rowp + 4 * (j3 > 127 ? 127 : j3));
  const int i4 = 4 * (Jb + 4);
  W.f16 = rowp[i4 > 511 ? 511 : i4];
}

__device__ __forceinline__ void load_win_fast(const float* __restrict__ rowp,
                                              int Jb, Win& W) {
  W.f3 = rowp[4 * Jb + 3];
  W.w1 = *(const float4*)(rowp + 4 * (Jb + 1));
  W.w2 = *(const float4*)(rowp + 4 * (Jb + 2));
  W.w3 = *(const float4*)(rowp + 4 * (Jb + 3));
  W.f16 = rowp[4 * (Jb + 4)];
}

__device__ __forceinline__ void win_fix(int Jb, Win& W) {
  if (4 * Jb + 3 < 0) W.f3 = 0.f;
  if (Jb + 1 < 0) W.w1 = make_float4(0.f, 0.f, 0.f, 0.f);
  if (Jb + 3 > 127) W.w3 = make_float4(0.f, 0.f, 0.f, 0.f);
  if (4 * (Jb + 4) > 511) W.f16 = 0.f;
}

__device__ __forceinline__ void win_vals(const Win& W, float v[14]) {
  v[0] = W.f3;
  v[1] = W.w1.x;  v[2] = W.w1.y;  v[3] = W.w1.z;  v[4] = W.w1.w;
  v[5] = W.w2.x;  v[6] = W.w2.y;  v[7] = W.w2.z;  v[8] = W.w2.w;
  v[9] = W.w3.x;  v[10] = W.w3.y; v[11] = W.w3.z; v[12] = W.w3.w;
  v[13] = W.f16;
}

__device__ __forceinline__ void fma4(float4& a, float g, const float4& v) {
  a.x = fmaf(g, v.x, a.x); a.y = fmaf(g, v.y, a.y);
  a.z = fmaf(g, v.z, a.z); a.w = fmaf(g, v.w, a.w);
}

// m1 = mu1, m2 = mu2, mss = E[a^2 + b^2], m12 = E[ab]
__device__ __forceinline__ float ssim_px(float m1, float m2, float mss, float m12) {
  const float C1 = 0.0001f, C2 = 0.0009f;
  const float mu1s = m1 * m1, mu2s = m2 * m2, mu12 = m1 * m2;
  const float num = (2.f * mu12 + C1) * (2.f * (m12 - mu12) + C2);
  const float den = (mu1s + mu2s + C1) * (mss - mu1s - mu2s + C2);
  return num * __builtin_amdgcn_rcpf(den);
}

__global__ __launch_bounds__(NTHREADS, 2) void ssim_main_kernel(
    const float* __restrict__ img1, const float* __restrict__ img2,
    float* __restrict__ partials, GW w, int nTiles)
{
  __shared__ __align__(16) float si[NF][IN_H][SIP];  // 78,144 B -> 2 blocks/CU
  __shared__ float sred[NTHREADS / 64];

  const int tid = threadIdx.x;
  float accSum = 0.f;

  for (int tile = blockIdx.x; tile < nTiles; tile += gridDim.x) {
    int t = tile;
    const int tx = t & 7;  t >>= 3;   // 512/TX = 8
    const int ty = t & 7;  t >>= 3;   // 512/TY = 8
    const float* __restrict__ p1 = img1 + (size_t)t * 262144;
    const float* __restrict__ p2 = img2 + (size_t)t * 262144;
    const int gy0 = ty * TY - 5;
    const bool edgeX = (tx == 0) | (tx == 7);

    // ---- horizontal pass: windows straight from global (L1), 4 px/item ----
    // items: 74 rows x 16 j-groups = 1184
    for (int i = tid; i < IN_H * 16; i += NTHREADS) {
      const int r = i >> 4, j = i & 15;
      const int jw = j ^ ((r >> 1) & 1);  // float4-granular swizzle
      const int gy = gy0 + r;
      if (gy >= 0 && gy < 512) {
        const int Jb = tx * 16 + j - 2;
        Win WA, WB;
        if (edgeX) {
          load_win_clamped(p1 + (size_t)gy * 512, Jb, WA);
          load_win_clamped(p2 + (size_t)gy * 512, Jb, WB);
          win_fix(Jb, WA); win_fix(Jb, WB);
        } else {
          load_win_fast(p1 + (size_t)gy * 512, Jb, WA);
          load_win_fast(p2 + (size_t)gy * 512, Jb, WB);
        }
        float a[14], b[14];
        win_vals(WA, a); win_vals(WB, b);
        float ss[14], ab[14];
#pragma unroll
        for (int q = 0; q < 14; q++) {
          ss[q] = fmaf(a[q], a[q], b[q] * b[q]);
          ab[q] = a[q] * b[q];
        }
        float m1[4] = {0, 0, 0, 0}, m2[4] = {0, 0, 0, 0},
              mss[4] = {0, 0, 0, 0}, m12[4] = {0, 0, 0, 0};
#pragma unroll
        for (int k = 0; k < WSZ; k++) {
          const float g = w.g[k];
#pragma unroll
          for (int x = 0; x < 4; x++) {
            m1[x]  = fmaf(g, a[x + k],  m1[x]);
            m2[x]  = fmaf(g, b[x + k],  m2[x]);
            mss[x] = fmaf(g, ss[x + k], mss[x]);
            m12[x] = fmaf(g, ab[x + k], m12[x]);
          }
        }
        *(float4*)&si[0][r][4 * jw] = make_float4(m1[0], m1[1], m1[2], m1[3]);
        *(float4*)&si[1][r][4 * jw] = make_float4(m2[0], m2[1], m2[2], m2[3]);
        *(float4*)&si[2][r][4 * jw] = make_float4(mss[0], mss[1], mss[2], mss[3]);
        *(float4*)&si[3][r][4 * jw] = make_float4(m12[0], m12[1], m12[2], m12[3]);
      } else {
        const float4 z = make_float4(0.f, 0.f, 0.f, 0.f);
#pragma unroll
        for (int f = 0; f < NF; f++) *(float4*)&si[f][r][4 * jw] = z;
      }
    }
    __syncthreads();

    // ---- vertical pass + SSIM: 4x x 4y per thread (256 items) ----
    {
      const int yi = tid >> 4, j = tid & 15;
      const int y0 = 4 * yi;
      float4 acc[4][NF];  // [y-output][field]
#pragma unroll
      for (int o = 0; o < 4; o++)
#pragma unroll
        for (int f = 0; f < NF; f++) acc[o][f] = make_float4(0.f, 0.f, 0.f, 0.f);
#pragma unroll
      for (int k = 0; k < WSZ + 3; k++) {
        const int rr = y0 + k;
        const int jw = j ^ ((rr >> 1) & 1);  // same involution as writes
        float4 v[NF];
#pragma unroll
        for (int f = 0; f < NF; f++) v[f] = *(const float4*)&si[f][rr][4 * jw];
#pragma unroll
        for (int o = 0; o < 4; o++) {
          if (k >= o && k - o < WSZ) {
            const float g = w.g[k - o];
#pragma unroll
            for (int f = 0; f < NF; f++) fma4(acc[o][f], g, v[f]);
          }
        }
      }
#pragma unroll
      for (int o = 0; o < 4; o++) {
        accSum += ssim_px(acc[o][0].x, acc[o][1].x, acc[o][2].x, acc[o][3].x);
        accSum += ssim_px(acc[o][0].y, acc[o][1].y, acc[o][2].y, acc[o][3].y);
        accSum += ssim_px(acc[o][0].z, acc[o][1].z, acc[o][2].z, acc[o][3].z);
        accSum += ssim_px(acc[o][0].w, acc[o][1].w, acc[o][2].w, acc[o][3].w);
      }
    }
    __syncthreads();  // protect si before next tile overwrites
  }

  // ---- block reduction ----
  for (int off = 32; off > 0; off >>= 1)
    accSum += __shfl_down(accSum, off, 64);
  if ((tid & 63) == 0) sred[tid >> 6] = accSum;
  __syncthreads();
  if (tid == 0) {
    float s = 0.f;
#pragma unroll
    for (int i = 0; i < NTHREADS / 64; i++) s += sred[i];
    partials[blockIdx.x] = s;
  }
}

__global__ __launch_bounds__(256) void ssim_final_kernel(
    const float* __restrict__ partials, float* __restrict__ out,
    int n, double invN)
{
  __shared__ double sred[4];
  const int tid = threadIdx.x;
  double s = 0.0;
  for (int i = tid; i < n; i += 256) s += (double)partials[i];
  for (int off = 32; off > 0; off >>= 1)
    s += __shfl_down(s, off, 64);
  if ((tid & 63) == 0) sred[tid >> 6] = s;
  __syncthreads();
  if (tid == 0) {
    double tot = 0.0;
#pragma unroll
    for (int i = 0; i < 4; i++) tot += sred[i];
    out[0] = (float)(1.0 - tot * invN);
  }
}

extern "C" void kernel_launch(void* const* d_in, const int* in_sizes, int n_in,
                              void* d_out, int out_size, void* d_ws, size_t ws_size,
                              hipStream_t stream) {
  const float* img1 = (const float*)d_in[0];
  const float* img2 = (const float*)d_in[1];
  float* out = (float*)d_out;
  float* partials = (float*)d_ws;

  const int planes = in_sizes[0] / (512 * 512);     // 96
  const int nTiles = planes * 8 * 8;                // 6144

  GW w;
  {
    double g[WSZ], sum = 0.0;
    for (int i = 0; i < WSZ; i++) {
      const double x = (double)(i - WSZ / 2);
      g[i] = exp(-(x * x) / (2.0 * 1.5 * 1.5));
      sum += g[i];
    }
    for (int i = 0; i < WSZ; i++) w.g[i] = (float)(g[i] / sum);
  }

  const double invN = 1.0 / (double)in_sizes[0];

  ssim_main_kernel<<<NBLOCKS, NTHREADS, 0, stream>>>(img1, img2, partials, w, nTiles);
  ssim_final_kernel<<<1, 256, 0, stream>>>(partials, out, NBLOCKS, invN);
}

// Round 8
// 91.197 us; speedup vs baseline: 2.6681x; 1.4129x over previous
//
#include <hip/hip_runtime.h>
#include <hip/hip_fp16.h>
#include <math.h>

#define WSZ 11
#define TX 64
#define TY 64
#define IN_H 74           // TY + 10
#define SIP 66            // si row stride (uint/half2 units)
#define NTHREADS 256
#define NBLOCKS 2048

struct GW { float g[WSZ]; };

struct Win { float f3; float4 w1, w2, w3; float f16; };

__device__ __forceinline__ void load_win_clamped(const float* __restrict__ rowp,
                                                 int Jb, Win& W) {
  const int i0 = 4 * Jb + 3;
  W.f3 = rowp[i0 < 0 ? 0 : i0];
  const int j1 = Jb + 1;
  W.w1 = *(const float4*)(rowp + 4 * (j1 < 0 ? 0 : j1));
  W.w2 = *(const float4*)(rowp + 4 * (Jb + 2));
  const int j3 = Jb + 3;
  W.w3 = *(const float4*)(rowp + 4 * (j3 > 127 ? 127 : j3));
  const int i4 = 4 * (Jb + 4);
  W.f16 = rowp[i4 > 511 ? 511 : i4];
}

__device__ __forceinline__ void load_win_fast(const float* __restrict__ rowp,
                                              int Jb, Win& W) {
  W.f3 = rowp[4 * Jb + 3];
  W.w1 = *(const float4*)(rowp + 4 * (Jb + 1));
  W.w2 = *(const float4*)(rowp + 4 * (Jb + 2));
  W.w3 = *(const float4*)(rowp + 4 * (Jb + 3));
  W.f16 = rowp[4 * (Jb + 4)];
}

__device__ __forceinline__ void win_fix(int Jb, Win& W) {
  if (4 * Jb + 3 < 0) W.f3 = 0.f;
  if (Jb + 1 < 0) W.w1 = make_float4(0.f, 0.f, 0.f, 0.f);
  if (Jb + 3 > 127) W.w3 = make_float4(0.f, 0.f, 0.f, 0.f);
  if (4 * (Jb + 4) > 511) W.f16 = 0.f;
}

__device__ __forceinline__ void win_vals(const Win& W, float v[14]) {
  v[0] = W.f3;
  v[1] = W.w1.x;  v[2] = W.w1.y;  v[3] = W.w1.z;  v[4] = W.w1.w;
  v[5] = W.w2.x;  v[6] = W.w2.y;  v[7] = W.w2.z;  v[8] = W.w2.w;
  v[9] = W.w3.x;  v[10] = W.w3.y; v[11] = W.w3.z; v[12] = W.w3.w;
  v[13] = W.f16;
}

// m1 = mu1, m2 = mu2, mss = E[a^2 + b^2], m12 = E[ab]
__device__ __forceinline__ float ssim_px(float m1, float m2, float mss, float m12) {
  const float C1 = 0.0001f, C2 = 0.0009f;
  const float mu1s = m1 * m1, mu2s = m2 * m2, mu12 = m1 * m2;
  const float num = (2.f * mu12 + C1) * (2.f * (m12 - mu12) + C2);
  const float den = (mu1s + mu2s + C1) * (mss - mu1s - mu2s + C2);
  return num * __builtin_amdgcn_rcpf(den);
}

__device__ __forceinline__ unsigned int h2u(__half2 h) {
  return __builtin_bit_cast(unsigned int, h);
}
__device__ __forceinline__ __half2 u2h(unsigned int u) {
  return __builtin_bit_cast(__half2, u);
}

__global__ __launch_bounds__(NTHREADS, 2) void ssim_main_kernel(
    const float* __restrict__ img1, const float* __restrict__ img2,
    float* __restrict__ partials, GW w, int nTiles)
{
  // two half2 streams: si0 = (a, b), si1 = (a^2+b^2, a*b)
  __shared__ __align__(16) unsigned int si0[IN_H][SIP];  // 19,536 B
  __shared__ __align__(16) unsigned int si1[IN_H][SIP];  // 19,536 B
  __shared__ float sred[NTHREADS / 64];

  const int tid = threadIdx.x;
  float accSum = 0.f;

  // packed tap weights, held in VGPRs for the whole kernel
  __half2 gh[WSZ];
#pragma unroll
  for (int k = 0; k < WSZ; k++) gh[k] = __float2half2_rn(w.g[k]);

  for (int tile = blockIdx.x; tile < nTiles; tile += gridDim.x) {
    int t = tile;
    const int tx = t & 7;  t >>= 3;   // 512/TX = 8
    const int ty = t & 7;  t >>= 3;   // 512/TY = 8
    const float* __restrict__ p1 = img1 + (size_t)t * 262144;
    const float* __restrict__ p2 = img2 + (size_t)t * 262144;
    const int gy0 = ty * TY - 5;
    const bool edgeX = (tx == 0) | (tx == 7);

    // ---- horizontal pass: windows from global (L1), 4 px/item, packed fp16 ----
    for (int i = tid; i < IN_H * 16; i += NTHREADS) {
      const int r = i >> 4, j = i & 15;
      const int jw = j ^ ((r >> 1) & 1);
      const int gy = gy0 + r;
      if (gy >= 0 && gy < 512) {
        const int Jb = tx * 16 + j - 2;
        Win WA, WB;
        if (edgeX) {
          load_win_clamped(p1 + (size_t)gy * 512, Jb, WA);
          load_win_clamped(p2 + (size_t)gy * 512, Jb, WB);
          win_fix(Jb, WA); win_fix(Jb, WB);
        } else {
          load_win_fast(p1 + (size_t)gy * 512, Jb, WA);
          load_win_fast(p2 + (size_t)gy * 512, Jb, WB);
        }
        float a[14], b[14];
        win_vals(WA, a); win_vals(WB, b);
        __half2 vab[14], vsb[14];
#pragma unroll
        for (int q = 0; q < 14; q++) {
          vab[q] = __float22half2_rn(make_float2(a[q], b[q]));
          const float ss = fmaf(a[q], a[q], b[q] * b[q]);
          const float ab = a[q] * b[q];
          vsb[q] = __float22half2_rn(make_float2(ss, ab));
        }
        __half2 hab[4], hsb[4];
#pragma unroll
        for (int x = 0; x < 4; x++) {
          hab[x] = u2h(0u); hsb[x] = u2h(0u);
        }
#pragma unroll
        for (int k = 0; k < WSZ; k++) {
          const __half2 g2 = gh[k];
#pragma unroll
          for (int x = 0; x < 4; x++) {
            hab[x] = __hfma2(g2, vab[x + k], hab[x]);
            hsb[x] = __hfma2(g2, vsb[x + k], hsb[x]);
          }
        }
        *(uint4*)&si0[r][4 * jw] =
            make_uint4(h2u(hab[0]), h2u(hab[1]), h2u(hab[2]), h2u(hab[3]));
        *(uint4*)&si1[r][4 * jw] =
            make_uint4(h2u(hsb[0]), h2u(hsb[1]), h2u(hsb[2]), h2u(hsb[3]));
      } else {
        const uint4 z = make_uint4(0u, 0u, 0u, 0u);
        *(uint4*)&si0[r][4 * jw] = z;
        *(uint4*)&si1[r][4 * jw] = z;
      }
    }
    __syncthreads();

    // ---- vertical pass + SSIM: 4x x 4y per thread, packed fp16 ----
    {
      const int yi = tid >> 4, j = tid & 15;
      const int y0 = 4 * yi;
      __half2 accA[4][4], accS[4][4];  // [y-output][px]
#pragma unroll
      for (int o = 0; o < 4; o++)
#pragma unroll
        for (int p = 0; p < 4; p++) {
          accA[o][p] = u2h(0u); accS[o][p] = u2h(0u);
        }
#pragma unroll
      for (int k = 0; k < WSZ + 3; k++) {
        const int rr = y0 + k;
        const int jw = j ^ ((rr >> 1) & 1);
        const uint4 ua = *(const uint4*)&si0[rr][4 * jw];
        const uint4 us = *(const uint4*)&si1[rr][4 * jw];
        const __half2 va[4] = {u2h(ua.x), u2h(ua.y), u2h(ua.z), u2h(ua.w)};
        const __half2 vs[4] = {u2h(us.x), u2h(us.y), u2h(us.z), u2h(us.w)};
#pragma unroll
        for (int o = 0; o < 4; o++) {
          if (k >= o && k - o < WSZ) {
            const __half2 g2 = gh[k - o];
#pragma unroll
            for (int p = 0; p < 4; p++) {
              accA[o][p] = __hfma2(g2, va[p], accA[o][p]);
              accS[o][p] = __hfma2(g2, vs[p], accS[o][p]);
            }
          }
        }
      }
#pragma unroll
      for (int o = 0; o < 4; o++)
#pragma unroll
        for (int p = 0; p < 4; p++) {
          const float2 mab = __half22float2(accA[o][p]);
          const float2 msb = __half22float2(accS[o][p]);
          accSum += ssim_px(mab.x, mab.y, msb.x, msb.y);
        }
    }
    __syncthreads();  // protect si before next tile overwrites
  }

  // ---- block reduction ----
  for (int off = 32; off > 0; off >>= 1)
    accSum += __shfl_down(accSum, off, 64);
  if ((tid & 63) == 0) sred[tid >> 6] = accSum;
  __syncthreads();
  if (tid == 0) {
    float s = 0.f;
#pragma unroll
    for (int i = 0; i < NTHREADS / 64; i++) s += sred[i];
    partials[blockIdx.x] = s;
  }
}

__global__ __launch_bounds__(256) void ssim_final_kernel(
    const float* __restrict__ partials, float* __restrict__ out,
    int n, double invN)
{
  __shared__ double sred[4];
  const int tid = threadIdx.x;
  double s = 0.0;
  for (int i = tid; i < n; i += 256) s += (double)partials[i];
  for (int off = 32; off > 0; off >>= 1)
    s += __shfl_down(s, off, 64);
  if ((tid & 63) == 0) sred[tid >> 6] = s;
  __syncthreads();
  if (tid == 0) {
    double tot = 0.0;
#pragma unroll
    for (int i = 0; i < 4; i++) tot += sred[i];
    out[0] = (float)(1.0 - tot * invN);
  }
}

extern "C" void kernel_launch(void* const* d_in, const int* in_sizes, int n_in,
                              void* d_out, int out_size, void* d_ws, size_t ws_size,
                              hipStream_t stream) {
  const float* img1 = (const float*)d_in[0];
  const float* img2 = (const float*)d_in[1];
  float* out = (float*)d_out;
  float* partials = (float*)d_ws;

  const int planes = in_sizes[0] / (512 * 512);     // 96
  const int nTiles = planes * 8 * 8;                // 6144

  GW w;
  {
    double g[WSZ], sum = 0.0;
    for (int i = 0; i < WSZ; i++) {
      const double x = (double)(i - WSZ / 2);
      g[i] = exp(-(x * x) / (2.0 * 1.5 * 1.5));
      sum += g[i];
    }
    for (int i = 0; i < WSZ; i++) w.g[i] = (float)(g[i] / sum);
  }

  const double invN = 1.0 / (double)in_sizes[0];

  ssim_main_kernel<<<NBLOCKS, NTHREADS, 0, stream>>>(img1, img2, partials, w, nTiles);
  ssim_final_kernel<<<1, 256, 0, stream>>>(partials, out, NBLOCKS, invN);
}